// Round 4
// baseline (170.783 us; speedup 1.0000x reference)
//
#include <hip/hip_runtime.h>

// DDLG autoencoder, fully fused, ALL-fp16 packed compute, batch-tile 8.
//   out[b][o] = sum_f prob[o][f] * op_f(x[b][idx[o][0..7]])
// R1: divide-free Einstein reductions via homomorphisms:
//     ein-product = 2D/(N+D),  D=prod(f), N=prod(2-f)
//     ein-sum     = (N-D)/(N+D), N=prod(1+f), D=prod(1-f)
// R7: idx pre-scale folded into addressing; prep_k is probs-only.
// R8: combined-denominator finale (one rcp pair per h2 over s1*s2; range
//     proof: s1*s2 <= 2.25^8 + 257 ~ 914 < 65504, numerators <= 912).
// R9: chain+finale in explicit 2-wide _Float16 (native v_pk_*_f16 width).
// R10 (this round): batch-tile 4 -> 8. Counter evidence: VALU-busy is ~2x
//     the pure-chain cycle count; the excess is per-GATE fixed cost (idx
//     address arith + global loads, 8 LDS addr calcs, ds issue, waits, P
//     splats). Doubling the batch tile halves ALL of it per output element;
//     chain cost per element is unchanged. One LDS row = 8 fp16 lanes
//     (16 B, ds_read_b128 gathers). Grid 512, block 1024, LDS 96 KB ->
//     1 block/CU, 16 waves (VALU oversubscription ~2.6x: enough to hide
//     L2/LDS latency). launch_bounds(1024,4): VGPR cap 128, no spill.
//     LDS overlays (fp16 rows of 8 = 16 B):
//       x @ [0,65536) B | h0 @ [65536,98304) B | h1 over dead x | h2 over dead h0

#define BATCH 4096

typedef _Float16 h2 __attribute__((ext_vector_type(2)));
typedef _Float16 h4 __attribute__((ext_vector_type(4)));

__device__ __forceinline__ float fastrcp(float x) { return __builtin_amdgcn_rcpf(x); }
__device__ __forceinline__ _Float16 hrcp(_Float16 x) {
#if __has_builtin(__builtin_amdgcn_rcph)
    return __builtin_amdgcn_rcph(x);
#else
    return (_Float16)__builtin_amdgcn_rcpf((float)x);
#endif
}
__device__ __forceinline__ h2 splat2(_Float16 s) { h2 v = {s, s}; return v; }

// ---------------- prep: fp16 prob table only ----------------
// probsH: [0,2048) L0 | [2048,3072) L1 | [3072,5120) L2 | [5120,9216) L3
__global__ __launch_bounds__(256) void prep_k(const float* __restrict__ w0,
                                              const float* __restrict__ w1,
                                              const float* __restrict__ w2,
                                              const float* __restrict__ w3,
                                              const int* __restrict__ is_train,
                                              h4* __restrict__ probsH) {
    const int g = blockIdx.x * 256 + threadIdx.x;   // grid 36 -> 9216 exact
    const float* w; int o;
    if (g < 2048)      { w = w0; o = g; }
    else if (g < 3072) { w = w1; o = g - 2048; }
    else if (g < 5120) { w = w2; o = g - 3072; }
    else               { w = w3; o = g - 5120; }
    float wv[4];
#pragma unroll
    for (int c = 0; c < 4; ++c) wv[c] = w[(o << 2) + c];
    float p[4];
    if (*is_train) {
        float m = fmaxf(fmaxf(wv[0], wv[1]), fmaxf(wv[2], wv[3]));
        float s = 0.0f;
#pragma unroll
        for (int c = 0; c < 4; ++c) { p[c] = __expf(wv[c] - m); s += p[c]; }
        float inv = fastrcp(s);
#pragma unroll
        for (int c = 0; c < 4; ++c) p[c] *= inv;
    } else {
        int a = 0; float best = wv[0];
#pragma unroll
        for (int c = 1; c < 4; ++c) if (wv[c] > best) { best = wv[c]; a = c; }
#pragma unroll
        for (int c = 0; c < 4; ++c) p[c] = (c == a) ? 1.0f : 0.0f;
    }
    probsH[g] = h4{(_Float16)p[0], (_Float16)p[1], (_Float16)p[2], (_Float16)p[3]};
}

// ---------------- one LDS row = 8 fp16 (batch lanes 0..7) as 4x h2 ----------------
struct Raw8 { h2 q[4]; };

__device__ __forceinline__ Raw8 row_at(const uint4* __restrict__ rows, int i) {
    const uint4 v = rows[i];                 // one ds_read_b128
    Raw8 r;
    r.q[0] = __builtin_bit_cast(h2, v.x);
    r.q[1] = __builtin_bit_cast(h2, v.y);
    r.q[2] = __builtin_bit_cast(h2, v.z);
    r.q[3] = __builtin_bit_cast(h2, v.w);
    return r;
}
__device__ __forceinline__ uint4 raw_bits(Raw8 r) {
    return uint4{__builtin_bit_cast(unsigned, r.q[0]), __builtin_bit_cast(unsigned, r.q[1]),
                 __builtin_bit_cast(unsigned, r.q[2]), __builtin_bit_cast(unsigned, r.q[3])};
}

// ---------------- chain state: 6 parallel reductions x 4 h2 quads ----------------
struct Chain8 { h2 mn[4], mx[4], De[4], Ne[4], Nc[4], Dc[4]; };

__device__ __forceinline__ void cinit(Chain8& C, Raw8 v) {
    const h2 one = splat2((_Float16)1.0f), two = splat2((_Float16)2.0f);
#pragma unroll
    for (int q = 0; q < 4; ++q) {
        C.mn[q] = v.q[q]; C.mx[q] = v.q[q]; C.De[q] = v.q[q];
        C.Ne[q] = two - v.q[q];
        C.Nc[q] = one + v.q[q];
        C.Dc[q] = one - v.q[q];
    }
}
__device__ __forceinline__ void cstep(Chain8& C, Raw8 v) {
    const h2 two = splat2((_Float16)2.0f);
#pragma unroll
    for (int q = 0; q < 4; ++q) {
        C.mn[q] = __builtin_elementwise_min(C.mn[q], v.q[q]);
        C.mx[q] = __builtin_elementwise_max(C.mx[q], v.q[q]);
        C.De[q] *= v.q[q];
        C.Ne[q] *= (two - v.q[q]);
        C.Nc[q] += C.Nc[q] * v.q[q];   // pk_fma: Nc *= (1+v)
        C.Dc[q] -= C.Dc[q] * v.q[q];   // pk_fma: Dc *= (1-v)
    }
}
// combined-denominator finale: one rcp pair per h2 serves both ein and coe.
__device__ __forceinline__ Raw8 finale(const Chain8& C, h4 P) {
    const h2 P0 = splat2(P[0]), P1 = splat2(P[1]);
    const h2 P2 = splat2(P[2]), P3 = splat2(P[3]);
    Raw8 res;
#pragma unroll
    for (int q = 0; q < 4; ++q) {
        h2 s1 = C.Ne[q] + C.De[q];     // [1, 257]
        h2 s2 = C.Nc[q] + C.Dc[q];     // [1, 257]
        h2 d1 = C.Nc[q] - C.Dc[q];     // [0, 256]
        h2 ss = s1 * s2;               // <= ~914: fp16-safe
        h2 r  = {hrcp(ss[0]), hrcp(ss[1])};
        h2 t1 = (C.De[q] + C.De[q]) * s2;   // <= 514
        h2 t2 = d1 * s1;                    // <= 912
        h2 num = P2 * t1 + P3 * t2;
        res.q[q] = P0 * C.mn[q] + P1 * C.mx[q] + num * r;
    }
    return res;
}

// ---------------- one gate, 8 batch lanes ----------------
__device__ __forceinline__ Raw8 gate8(const uint4* __restrict__ rows,
                                      const int4* __restrict__ idx,
                                      const h4* __restrict__ probs, int o) {
    const int4 i0 = idx[o * 2], i1 = idx[o * 2 + 1];
    const h4 P = probs[o];
    Raw8 A[8];
    A[0] = row_at(rows, i0.x); A[1] = row_at(rows, i0.y);
    A[2] = row_at(rows, i0.z); A[3] = row_at(rows, i0.w);
    A[4] = row_at(rows, i1.x); A[5] = row_at(rows, i1.y);
    A[6] = row_at(rows, i1.z); A[7] = row_at(rows, i1.w);
    Chain8 C; cinit(C, A[0]);
#pragma unroll
    for (int c = 1; c < 8; ++c) cstep(C, A[c]);
    return finale(C, P);
}

// ---------------- the fused network ----------------
// grid = 512 (one block per 8-batch tile), block = 1024, 96 KB LDS, 1 block/CU
__global__ __launch_bounds__(1024, 4) void ddlg_fused(const float* __restrict__ x,
                                                      const h4* __restrict__ probsH,
                                                      const int4* __restrict__ idx0,
                                                      const int4* __restrict__ idx1,
                                                      const int4* __restrict__ idx2,
                                                      const int4* __restrict__ idx3,
                                                      float* __restrict__ out) {
    __shared__ __align__(16) _Float16 lds[49152];   // 96 KB
    const int t  = threadIdx.x;
    const int b0 = blockIdx.x << 3;

    const uint4* xv  = (const uint4*)lds;            // rows [0,4096), 64 KB
    const uint4* h0v = (const uint4*)(lds + 32768);  // rows [0,2048), 32 KB
    const uint4* h1v = (const uint4*)lds;            // rows [0,1024) (over dead x)
    const uint4* h2v = (const uint4*)(lds + 32768);  // rows [0,2048) (over dead h0)

    // ---- stage x: thread owns rows j = t + c*1024; 8 coalesced loads/row ----
#pragma unroll
    for (int c = 0; c < 4; ++c) {
        const int j = (c << 10) + t;
        h2 p[4];
#pragma unroll
        for (int qq = 0; qq < 4; ++qq) {
            const float va = x[(size_t)(b0 + 2 * qq + 0) * 4096 + j];
            const float vb = x[(size_t)(b0 + 2 * qq + 1) * 4096 + j];
            p[qq] = h2{(_Float16)va, (_Float16)vb};
        }
        uint4 hv = {__builtin_bit_cast(unsigned, p[0]), __builtin_bit_cast(unsigned, p[1]),
                    __builtin_bit_cast(unsigned, p[2]), __builtin_bit_cast(unsigned, p[3])};
        *(uint4*)(lds + (j << 3)) = hv;   // contiguous ds_write_b128: conflict-free
    }
    __syncthreads();

    // ---- L0: 4096 -> 2048, thread owns o = 2t, 2t+1 ----
    {
        Raw8 ra = gate8(xv, idx0, probsH, 2 * t);
        Raw8 rb = gate8(xv, idx0, probsH, 2 * t + 1);
        *(uint4*)(lds + 32768 + (t << 4))     = raw_bits(ra);   // row 2t
        *(uint4*)(lds + 32768 + (t << 4) + 8) = raw_bits(rb);   // row 2t+1
    }
    __syncthreads();

    // ---- L1: 2048 -> 1024, thread owns o = t ----
    {
        Raw8 r = gate8(h0v, idx1, probsH + 2048, t);
        *(uint4*)(lds + (t << 3)) = raw_bits(r);
    }
    __syncthreads();

    // ---- L2: 1024 -> 2048, thread owns o = 2t, 2t+1 ----
    {
        Raw8 ra = gate8(h1v, idx2, probsH + 3072, 2 * t);
        Raw8 rb = gate8(h1v, idx2, probsH + 3072, 2 * t + 1);
        *(uint4*)(lds + 32768 + (t << 4))     = raw_bits(ra);
        *(uint4*)(lds + 32768 + (t << 4) + 8) = raw_bits(rb);
    }
    __syncthreads();

    // ---- L3: 2048 -> 4096, thread owns o = 4t..4t+3; float4 stores x8 rows ----
    {
        Raw8 r0 = gate8(h2v, idx3, probsH + 5120, 4 * t);
        Raw8 r1 = gate8(h2v, idx3, probsH + 5120, 4 * t + 1);
        Raw8 r2 = gate8(h2v, idx3, probsH + 5120, 4 * t + 2);
        Raw8 r3 = gate8(h2v, idx3, probsH + 5120, 4 * t + 3);
#pragma unroll
        for (int b = 0; b < 8; ++b) {
            const int q = b >> 1, e = b & 1;
            float4 o4 = make_float4((float)r0.q[q][e], (float)r1.q[q][e],
                                    (float)r2.q[q][e], (float)r3.q[q][e]);
            *(float4*)(out + (size_t)(b0 + b) * 4096 + (t << 2)) = o4;
        }
    }
}

extern "C" void kernel_launch(void* const* d_in, const int* in_sizes, int n_in,
                              void* d_out, int out_size, void* d_ws, size_t ws_size,
                              hipStream_t stream) {
    const float* x        = (const float*)d_in[0];
    const float* w0       = (const float*)d_in[1];
    const float* w1       = (const float*)d_in[2];
    const float* w2       = (const float*)d_in[3];
    const float* w3       = (const float*)d_in[4];
    const int4*  idx0     = (const int4*)d_in[5];
    const int4*  idx1     = (const int4*)d_in[6];
    const int4*  idx2     = (const int4*)d_in[7];
    const int4*  idx3     = (const int4*)d_in[8];
    const int*   is_train = (const int*)d_in[9];
    float*       out      = (float*)d_out;

    // ws: probsH 9216*8B = 72 KB @0
    h4* probsH = (h4*)d_ws;

    prep_k<<<36, 256, 0, stream>>>(w0, w1, w2, w3, is_train, probsH);
    ddlg_fused<<<512, 1024, 0, stream>>>(x, probsH, idx0, idx1, idx2, idx3, out);
}

// Round 5
// 167.479 us; speedup vs baseline: 1.0197x; 1.0197x over previous
//
#include <hip/hip_runtime.h>

// DDLG autoencoder, SINGLE fused dispatch, batch-tile 4, ALL-fp16 packed compute.
//   out[b][o] = sum_f prob[o][f] * op_f(x[b][idx[o][0..7]])
// R1: divide-free Einstein reductions via homomorphisms:
//     ein-product = 2D/(N+D),  D=prod(f), N=prod(2-f)
//     ein-sum     = (N-D)/(N+D), N=prod(1+f), D=prod(1-f)
// R8: combined-denominator finale (one rcp pair per h2 over s1*s2; range
//     proof: s1*s2 <= 2.25^8 + 257 ~ 914 < 65504, numerators <= 912).
// R9: chain+finale in explicit 2-wide _Float16 (native v_pk_*_f16 width).
// R11 (this round) -- counters said latency/barrier-bound, nothing saturated
//     (real VALU ~28%, LDS ~20%, HBM 19%; only wave-structure ever moved dur):
//   - 512-thread blocks, batch-4, 48 KB LDS -> 3 blocks/CU (24 waves).
//     Barriers couple 8 waves (was 16); 3 resident blocks sit at different
//     phases so one block's chains cover another's gather latency; per-thread
//     gates per phase double (L0:4, L1:2, L2:4, L3:8) -> 2x ILP on the
//     phase critical path. launch_bounds(512,6) caps VGPR at 84 (3 blocks).
//   - prep_k deleted: per-gate softmax inlined (one float4 w load, L2-hot,
//     + ~15 fp32 ops + 4 expf; identical math -> identical absmax). One
//     dispatch, no workspace, no inter-kernel serialization.
//     LDS overlays (fp16 rows of 4 = 8 B, ds_read_b64 gathers):
//       x @ [0,16384) | h0 @ [16384,24576) | h1 @ [0,4096) | h2 @ [16384,24576)
//       (element offsets; bytes = 2x)

#define BATCH 4096

typedef _Float16 h2 __attribute__((ext_vector_type(2)));

__device__ __forceinline__ float fastrcp(float x) { return __builtin_amdgcn_rcpf(x); }
__device__ __forceinline__ _Float16 hrcp(_Float16 x) {
#if __has_builtin(__builtin_amdgcn_rcph)
    return __builtin_amdgcn_rcph(x);
#else
    return (_Float16)__builtin_amdgcn_rcpf((float)x);
#endif
}
__device__ __forceinline__ h2 splat2(_Float16 s) { h2 v = {s, s}; return v; }

// ---------------- inline per-gate softmax (identical math to old prep_k) ----------------
__device__ __forceinline__ void probs_of(const float* __restrict__ w, int o,
                                         bool train, _Float16 P[4]) {
    const float4 wv = ((const float4*)w)[o];
    float v0 = wv.x, v1 = wv.y, v2 = wv.z, v3 = wv.w;
    if (train) {
        float m = fmaxf(fmaxf(v0, v1), fmaxf(v2, v3));
        float e0 = __expf(v0 - m), e1 = __expf(v1 - m);
        float e2 = __expf(v2 - m), e3 = __expf(v3 - m);
        float inv = fastrcp(e0 + e1 + e2 + e3);
        P[0] = (_Float16)(e0 * inv); P[1] = (_Float16)(e1 * inv);
        P[2] = (_Float16)(e2 * inv); P[3] = (_Float16)(e3 * inv);
    } else {
        // first-max argmax scan (matches reference one_hot(argmax) semantics)
        int a = 0; float best = v0;
        if (v1 > best) { best = v1; a = 1; }
        if (v2 > best) { best = v2; a = 2; }
        if (v3 > best) { best = v3; a = 3; }
        P[0] = (_Float16)(a == 0 ? 1.0f : 0.0f);
        P[1] = (_Float16)(a == 1 ? 1.0f : 0.0f);
        P[2] = (_Float16)(a == 2 ? 1.0f : 0.0f);
        P[3] = (_Float16)(a == 3 ? 1.0f : 0.0f);
    }
}

// ---------------- one LDS row = 4 fp16 (batch lanes 0..3) as 2x h2 ----------------
struct Raw { h2 lo, hi; };

__device__ __forceinline__ Raw row_at(const uint2* __restrict__ rows, int i) {
    const uint2 v = rows[i];                 // one ds_read_b64
    Raw r;
    r.lo = __builtin_bit_cast(h2, v.x);
    r.hi = __builtin_bit_cast(h2, v.y);
    return r;
}
__device__ __forceinline__ uint2 raw_bits(Raw r) {
    return uint2{__builtin_bit_cast(unsigned, r.lo), __builtin_bit_cast(unsigned, r.hi)};
}

// ---------------- chain state: 6 parallel reductions x 2 halves ----------------
struct Chain { h2 mn0, mn1, mx0, mx1, De0, De1, Ne0, Ne1, Nc0, Nc1, Dc0, Dc1; };

__device__ __forceinline__ void cinit(Chain& C, Raw v) {
    const h2 one = splat2((_Float16)1.0f), two = splat2((_Float16)2.0f);
    C.mn0 = v.lo; C.mx0 = v.lo; C.De0 = v.lo;
    C.Ne0 = two - v.lo; C.Nc0 = one + v.lo; C.Dc0 = one - v.lo;
    C.mn1 = v.hi; C.mx1 = v.hi; C.De1 = v.hi;
    C.Ne1 = two - v.hi; C.Nc1 = one + v.hi; C.Dc1 = one - v.hi;
}
__device__ __forceinline__ void cstep(Chain& C, Raw v) {
    const h2 two = splat2((_Float16)2.0f);
    C.mn0 = __builtin_elementwise_min(C.mn0, v.lo);
    C.mn1 = __builtin_elementwise_min(C.mn1, v.hi);
    C.mx0 = __builtin_elementwise_max(C.mx0, v.lo);
    C.mx1 = __builtin_elementwise_max(C.mx1, v.hi);
    C.De0 *= v.lo;            C.De1 *= v.hi;
    C.Ne0 *= (two - v.lo);    C.Ne1 *= (two - v.hi);
    C.Nc0 += C.Nc0 * v.lo;    C.Nc1 += C.Nc1 * v.hi;   // pk_fma: Nc *= (1+v)
    C.Dc0 -= C.Dc0 * v.lo;    C.Dc1 -= C.Dc1 * v.hi;   // pk_fma: Dc *= (1-v)
}
// combined-denominator finale: one rcp pair per half serves both ein and coe.
__device__ __forceinline__ Raw finale(const Chain& C, const _Float16 P[4]) {
    h2 s10 = C.Ne0 + C.De0, s11 = C.Ne1 + C.De1;   // [1, 257]
    h2 s20 = C.Nc0 + C.Dc0, s21 = C.Nc1 + C.Dc1;   // [1, 257]
    h2 d10 = C.Nc0 - C.Dc0, d11 = C.Nc1 - C.Dc1;   // [0, 256]
    h2 ss0 = s10 * s20,     ss1 = s11 * s21;       // <= ~914: fp16-safe
    h2 r0 = {hrcp(ss0[0]), hrcp(ss0[1])};
    h2 r1 = {hrcp(ss1[0]), hrcp(ss1[1])};
    h2 t10 = (C.De0 + C.De0) * s20, t11 = (C.De1 + C.De1) * s21;  // <= 514
    h2 t20 = d10 * s10,             t21 = d11 * s11;              // <= 912
    const h2 P0 = splat2(P[0]), P1 = splat2(P[1]);
    const h2 P2 = splat2(P[2]), P3 = splat2(P[3]);
    h2 num0 = P2 * t10 + P3 * t20;
    h2 num1 = P2 * t11 + P3 * t21;
    Raw res;
    res.lo = P0 * C.mn0 + P1 * C.mx0 + num0 * r0;
    res.hi = P0 * C.mn1 + P1 * C.mx1 + num1 * r1;
    return res;
}

// ---------------- one gate, 4 batch lanes, inline probs ----------------
__device__ __forceinline__ Raw gate(const uint2* __restrict__ rows,
                                    const int4* __restrict__ idx,
                                    const float* __restrict__ w,
                                    bool train, int o) {
    const int4 i0 = idx[o * 2], i1 = idx[o * 2 + 1];
    _Float16 P[4];
    probs_of(w, o, train, P);
    Raw A[8];
    A[0] = row_at(rows, i0.x); A[1] = row_at(rows, i0.y);
    A[2] = row_at(rows, i0.z); A[3] = row_at(rows, i0.w);
    A[4] = row_at(rows, i1.x); A[5] = row_at(rows, i1.y);
    A[6] = row_at(rows, i1.z); A[7] = row_at(rows, i1.w);
    Chain C; cinit(C, A[0]);
#pragma unroll
    for (int c = 1; c < 8; ++c) cstep(C, A[c]);
    return finale(C, P);
}

// ---------------- the fused network ----------------
// grid = 1024 (one block per 4-batch tile), block = 512, 48 KB LDS, 3 blocks/CU
__global__ __launch_bounds__(512, 6) void ddlg_fused(const float* __restrict__ x,
                                                     const float* __restrict__ w0,
                                                     const float* __restrict__ w1,
                                                     const float* __restrict__ w2,
                                                     const float* __restrict__ w3,
                                                     const int* __restrict__ is_train,
                                                     const int4* __restrict__ idx0,
                                                     const int4* __restrict__ idx1,
                                                     const int4* __restrict__ idx2,
                                                     const int4* __restrict__ idx3,
                                                     float* __restrict__ out) {
    __shared__ __align__(16) _Float16 lds[24576];   // 48 KB
    const int t  = threadIdx.x;
    const int b0 = blockIdx.x << 2;
    const bool train = (*is_train) != 0;

    const uint2* xl  = (const uint2*)lds;            // rows [0,4096)
    const uint2* h0v = (const uint2*)(lds + 16384);  // rows [0,2048)
    const uint2* h1v = (const uint2*)lds;            // rows [0,1024) (over dead x)
    const uint2* h2v = (const uint2*)(lds + 16384);  // rows [0,2048) (over dead h0)

    // ---- stage x: thread owns rows j = t + 512c; 4 coalesced loads/row ----
#pragma unroll
    for (int c = 0; c < 8; ++c) {
        const int j = (c << 9) + t;
        const float v0 = x[(size_t)(b0 + 0) * 4096 + j];
        const float v1 = x[(size_t)(b0 + 1) * 4096 + j];
        const float v2 = x[(size_t)(b0 + 2) * 4096 + j];
        const float v3 = x[(size_t)(b0 + 3) * 4096 + j];
        h2 a = {(_Float16)v0, (_Float16)v1};
        h2 b = {(_Float16)v2, (_Float16)v3};
        uint2 hv = {__builtin_bit_cast(unsigned, a), __builtin_bit_cast(unsigned, b)};
        *(uint2*)(lds + (j << 2)) = hv;  // stride-8B ds_write_b64: conflict-free
    }
    __syncthreads();

    // ---- L0: 4096 -> 2048, thread owns o = t + 512k, k=0..3 (4-way ILP) ----
#pragma unroll
    for (int k = 0; k < 4; ++k) {
        const int o = (k << 9) + t;
        Raw r = gate(xl, idx0, w0, train, o);
        *(uint2*)(lds + 16384 + (o << 2)) = raw_bits(r);  // stride-8B: conflict-free
    }
    __syncthreads();

    // ---- L1: 2048 -> 1024, thread owns o = t + 512k, k=0..1 ----
#pragma unroll
    for (int k = 0; k < 2; ++k) {
        const int o = (k << 9) + t;
        Raw r = gate(h0v, idx1, w1, train, o);
        *(uint2*)(lds + (o << 2)) = raw_bits(r);
    }
    __syncthreads();

    // ---- L2: 1024 -> 2048, thread owns o = t + 512k, k=0..3 ----
#pragma unroll
    for (int k = 0; k < 4; ++k) {
        const int o = (k << 9) + t;
        Raw r = gate(h1v, idx2, w2, train, o);
        *(uint2*)(lds + 16384 + (o << 2)) = raw_bits(r);
    }
    __syncthreads();

    // ---- L3: 2048 -> 4096, thread owns o = t + 512k, k=0..7; coalesced stores ----
#pragma unroll
    for (int k = 0; k < 8; ++k) {
        const int o = (k << 9) + t;
        Raw r = gate(h2v, idx3, w3, train, o);
        out[(size_t)(b0 + 0) * 4096 + o] = (float)r.lo[0];
        out[(size_t)(b0 + 1) * 4096 + o] = (float)r.lo[1];
        out[(size_t)(b0 + 2) * 4096 + o] = (float)r.hi[0];
        out[(size_t)(b0 + 3) * 4096 + o] = (float)r.hi[1];
    }
}

extern "C" void kernel_launch(void* const* d_in, const int* in_sizes, int n_in,
                              void* d_out, int out_size, void* d_ws, size_t ws_size,
                              hipStream_t stream) {
    const float* x        = (const float*)d_in[0];
    const float* w0       = (const float*)d_in[1];
    const float* w1       = (const float*)d_in[2];
    const float* w2       = (const float*)d_in[3];
    const float* w3       = (const float*)d_in[4];
    const int4*  idx0     = (const int4*)d_in[5];
    const int4*  idx1     = (const int4*)d_in[6];
    const int4*  idx2     = (const int4*)d_in[7];
    const int4*  idx3     = (const int4*)d_in[8];
    const int*   is_train = (const int*)d_in[9];
    float*       out      = (float*)d_out;

    (void)d_ws; (void)ws_size;  // no workspace needed anymore

    ddlg_fused<<<1024, 512, 0, stream>>>(x, w0, w1, w2, w3, is_train,
                                         idx0, idx1, idx2, idx3, out);
}